// Round 7
// baseline (38.267 us; speedup 1.0000x reference)
//
#include <hip/hip_runtime.h>

// out[z, k] = sum_{n in segment(k)} vals[n] * x1[z, i_idx[n]] * x2[z, j_idx[n]]
//
// Structure facts (from the reference generator _build_sparse_tp):
//  * entries are ordered so that every output row k is ONE contiguous run in n
//    -- runs are in generator path order, NOT ascending k. Bounds live in
//       per-k seg_start/seg_end (row_ptr CSR is WRONG — R4 failure).
//  * every k in [0, dim_out) appears => boundary detection fully populates
//    both arrays, no memset needed (verified R3/R5/R6).
//
// R7: pipe-overlap fix. Per-CU budget (nnz~60K): LDS 9.3us + VALU 9.3us +
// store-BW 13.5us; R3-R6 measured ~ the SUM (no overlap). Change: split the
// 16-z accumulation into 4 z-quads; store each quad's 4 rows immediately so
// stores interleave with the next quad's LDS/FMA work. Entry stream re-read
// per quad (12KB/block, L1-resident). T14 stage: global->reg at kernel entry,
// ds_write just before barrier. Keep R3 concurrency (BLK=512, 23KB LDS).

#define ZPT 16
#define BLK 512
#define DIM_IN 144
#define STRIDE 20      // dwords; multiple of 4 -> 16B-aligned b128 rows

__global__ void prep_kernel(const int* __restrict__ k_idx,
                            const float* __restrict__ vals,
                            const int* __restrict__ i_idx,
                            const int* __restrict__ j_idx,
                            int nnz,
                            int* __restrict__ seg_start,
                            int* __restrict__ seg_end,
                            int2* __restrict__ packed) {
    int n = blockIdx.x * blockDim.x + threadIdx.x;
    if (n >= nnz) return;
    int k = k_idx[n];
    if (n == 0 || k_idx[n - 1] != k) seg_start[k] = n;
    if (n == nnz - 1 || k_idx[n + 1] != k) seg_end[k] = n + 1;
    packed[n] = make_int2(i_idx[n] | (j_idx[n] << 16), __float_as_int(vals[n]));
}

__global__ __launch_bounds__(BLK) void tp_kernel(
        const float* __restrict__ x1,
        const float* __restrict__ x2,
        const int2* __restrict__ packed,
        const int* __restrict__ seg_start,
        const int* __restrict__ seg_end,
        float* __restrict__ out,
        int dim_out) {
    __shared__ __align__(16) float x1s[DIM_IN * STRIDE];
    __shared__ __align__(16) float x2s[DIM_IN * STRIDE];

    const int z0 = blockIdx.y * ZPT;
    const int k  = blockIdx.x * BLK + threadIdx.x;
    const bool live = (k < dim_out);

    // ---- T14 stage, part 1: issue global loads into registers NOW ----
    // 2*576 float4 slots over 512 threads: slot t0 = tid, t1 = tid + BLK.
    const int n4 = ZPT * (DIM_IN / 4);   // 576
    const int s0 = threadIdx.x;
    const int s1 = threadIdx.x + BLK;
    float4 a0, b0, a1, b1;
    {
        const int t  = s0 / (DIM_IN / 4);
        const int i4 = s0 % (DIM_IN / 4);
        a0 = *(const float4*)(x1 + (size_t)(z0 + t) * DIM_IN + i4 * 4);
        b0 = *(const float4*)(x2 + (size_t)(z0 + t) * DIM_IN + i4 * 4);
    }
    if (s1 < n4) {
        const int t  = s1 / (DIM_IN / 4);
        const int i4 = s1 % (DIM_IN / 4);
        a1 = *(const float4*)(x1 + (size_t)(z0 + t) * DIM_IN + i4 * 4);
        b1 = *(const float4*)(x2 + (size_t)(z0 + t) * DIM_IN + i4 * 4);
    }

    // bounds loads overlap the stage-load latency
    int s = 0, e = 0;
    if (live) {
        s = seg_start[k];
        e = seg_end[k];
    }

    // ---- T14 stage, part 2: write registers to LDS (transposed) ----
    {
        const int t  = s0 / (DIM_IN / 4);
        const int i4 = s0 % (DIM_IN / 4);
        const int base = i4 * 4 * STRIDE + t;
        x1s[base             ] = a0.x;
        x1s[base +     STRIDE] = a0.y;
        x1s[base + 2 * STRIDE] = a0.z;
        x1s[base + 3 * STRIDE] = a0.w;
        x2s[base             ] = b0.x;
        x2s[base +     STRIDE] = b0.y;
        x2s[base + 2 * STRIDE] = b0.z;
        x2s[base + 3 * STRIDE] = b0.w;
    }
    if (s1 < n4) {
        const int t  = s1 / (DIM_IN / 4);
        const int i4 = s1 % (DIM_IN / 4);
        const int base = i4 * 4 * STRIDE + t;
        x1s[base             ] = a1.x;
        x1s[base +     STRIDE] = a1.y;
        x1s[base + 2 * STRIDE] = a1.z;
        x1s[base + 3 * STRIDE] = a1.w;
        x2s[base             ] = b1.x;
        x2s[base +     STRIDE] = b1.y;
        x2s[base + 2 * STRIDE] = b1.z;
        x2s[base + 3 * STRIDE] = b1.w;
    }
    __syncthreads();

    if (!live) return;

    // ---- gather + store, one z-quad at a time (stores interleave) ----
#pragma unroll
    for (int q = 0; q < ZPT / 4; ++q) {
        float ac0 = 0.0f, ac1 = 0.0f, ac2 = 0.0f, ac3 = 0.0f;

        int n = s;
        if (n < e) {
            int2 ev = packed[n];
            for (;;) {
                const bool more = (n + 1 < e);
                int2 evn;
                if (more) evn = packed[n + 1];

                const float c = __int_as_float(ev.y);
                const int i = ev.x & 0xffff;
                const int j = ev.x >> 16;
                const float4 a = *(const float4*)(x1s + i * STRIDE + 4 * q);
                const float4 b = *(const float4*)(x2s + j * STRIDE + 4 * q);
                ac0 += c * a.x * b.x;
                ac1 += c * a.y * b.y;
                ac2 += c * a.z * b.z;
                ac3 += c * a.w * b.w;

                ++n;
                if (!more) break;
                ev = evn;
            }
        }

        float* o = out + (size_t)(z0 + 4 * q) * dim_out + k;
        o[0]                    = ac0;
        o[(size_t)dim_out]      = ac1;
        o[(size_t)2 * dim_out]  = ac2;
        o[(size_t)3 * dim_out]  = ac3;
    }
}

extern "C" void kernel_launch(void* const* d_in, const int* in_sizes, int n_in,
                              void* d_out, int out_size, void* d_ws, size_t ws_size,
                              hipStream_t stream) {
    const float* x1   = (const float*)d_in[0];
    const float* x2   = (const float*)d_in[1];
    const float* vals = (const float*)d_in[2];
    const int*   kidx = (const int*)d_in[3];
    const int*   iidx = (const int*)d_in[4];
    const int*   jidx = (const int*)d_in[5];
    float* out = (float*)d_out;

    const int n_batch = 1024;                  // N_BATCH in the reference
    const int dim_out = out_size / n_batch;    // 20736
    const int nnz     = in_sizes[2];

    // workspace: seg_start[dim_out], seg_end[dim_out], packed int2[nnz]
    int*  seg_start = (int*)d_ws;
    int*  seg_end   = seg_start + dim_out;
    int2* packed    = (int2*)(seg_end + dim_out);   // 8B-aligned

    {
        int grid = (nnz + 255) / 256;
        prep_kernel<<<grid, 256, 0, stream>>>(kidx, vals, iidx, jidx, nnz,
                                              seg_start, seg_end, packed);
    }

    {
        dim3 grid((dim_out + BLK - 1) / BLK, 1024 / ZPT);
        tp_kernel<<<grid, BLK, 0, stream>>>(x1, x2, packed,
                                            seg_start, seg_end, out, dim_out);
    }
}